// Round 1
// baseline (1314.974 us; speedup 1.0000x reference)
//
#include <hip/hip_runtime.h>
#include <math.h>

#define NB 32768
#define NT 48
#define NH 32
#define NOH 16
#define NK 3
#define NS 6
#define NSUB 4

// tanh(x) = 1 - 2/(exp(2x)+1): robust for all x (inf -> 1, 0 -> -1 paths ok)
__device__ __forceinline__ float fast_tanh(float x) {
    float e = __builtin_amdgcn_exp2f(2.88539008177792681472f * x); // 2*log2(e)
    return 1.0f - 2.0f * __builtin_amdgcn_rcpf(e + 1.0f);
}

__device__ __forceinline__ float gelu_exact(float x) {
    return 0.5f * x * (1.0f + erff(x * 0.70710678118654752440f));
}

__global__ void __launch_bounds__(64, 1) pinod_kernel(
    const float* __restrict__ expr,
    const float* __restrict__ t_eval,
    const float* __restrict__ enc_w1,
    const float* __restrict__ enc_b1,
    const float* __restrict__ ln_g,
    const float* __restrict__ ln_b,
    const float* __restrict__ enc_w2,
    const float* __restrict__ enc_b2,
    const float* __restrict__ enc_w3,
    const float* __restrict__ enc_b3,
    const float* __restrict__ periods,
    const float* __restrict__ gammav,
    const float* __restrict__ ode_w1,
    const float* __restrict__ ode_b1,
    const float* __restrict__ ode_w2,
    const float* __restrict__ ode_b2,
    const float* __restrict__ dec_w,
    const float* __restrict__ dec_b,
    const float* __restrict__ baseline,
    float* __restrict__ out)
{
    const int b = blockIdx.x * 64 + threadIdx.x;

    float* out_eh  = out;                                        // [NB][NT]
    float* out_tr  = out + (size_t)NB * NT;                      // [NT][NB][NS]
    float* out_amp = out + (size_t)NB * NT + (size_t)NT * NB * NS; // [NB][NK]

    // ---------------- encoder ----------------
    float h1[NH];
    #pragma unroll
    for (int j = 0; j < NH; ++j) h1[j] = enc_b1[j];

    const float4* xp = (const float4*)(expr + (size_t)b * NT);
    #pragma unroll 1
    for (int t4 = 0; t4 < NT / 4; ++t4) {
        float4 xq = xp[t4];
        float xs[4] = {xq.x, xq.y, xq.z, xq.w};
        #pragma unroll
        for (int u = 0; u < 4; ++u) {
            #pragma unroll
            for (int j = 0; j < NH; ++j)
                h1[j] = fmaf(xs[u], enc_w1[(t4 * 4 + u) * NH + j], h1[j]);
        }
    }

    // layernorm + gelu
    float mu = 0.f;
    #pragma unroll
    for (int j = 0; j < NH; ++j) mu += h1[j];
    mu *= (1.0f / NH);
    float var = 0.f;
    #pragma unroll
    for (int j = 0; j < NH; ++j) { float d = h1[j] - mu; var = fmaf(d, d, var); }
    var *= (1.0f / NH);
    float rstd = rsqrtf(var + 1e-5f);
    #pragma unroll
    for (int j = 0; j < NH; ++j) {
        float v = (h1[j] - mu) * rstd * ln_g[j] + ln_b[j];
        h1[j] = gelu_exact(v);
    }

    // h2 = gelu(h1 @ w2 + b2); z0 = h2 @ w3 + b3 (fused, one hidden unit at a time)
    float z[NS];
    #pragma unroll
    for (int s = 0; s < NS; ++s) z[s] = enc_b3[s];
    #pragma unroll 1
    for (int j2 = 0; j2 < NH; ++j2) {
        float acc = enc_b2[j2];
        #pragma unroll
        for (int j = 0; j < NH; ++j) acc = fmaf(h1[j], enc_w2[j * NH + j2], acc);
        float g = gelu_exact(acc);
        #pragma unroll
        for (int s = 0; s < NS; ++s) z[s] = fmaf(g, enc_w3[j2 * NS + s], z[s]);
    }

    // ---------------- ODE params (wave-uniform) ----------------
    float om2[NK], tg[NK], dw[NK];
    #pragma unroll
    for (int k = 0; k < NK; ++k) {
        float w = 6.28318530717958647693f / periods[k];
        om2[k] = w * w;
        tg[k]  = 2.0f * gammav[k];
        dw[k]  = dec_w[k];
    }
    const float addc = dec_b[0] + baseline[0];

    auto deriv = [&](const float (&zz)[NS], float (&d)[NS]) {
        #pragma unroll
        for (int k = 0; k < NK; ++k) {
            float xx = zz[2 * k], vv = zz[2 * k + 1];
            d[2 * k]     = vv;
            d[2 * k + 1] = -om2[k] * xx - tg[k] * vv;
        }
        #pragma unroll
        for (int j = 0; j < NOH; ++j) {
            float a = ode_b1[j];
            #pragma unroll
            for (int i = 0; i < NS; ++i) a = fmaf(zz[i], ode_w1[i * NOH + j], a);
            float y = fast_tanh(a);
            #pragma unroll
            for (int i = 0; i < NS; ++i) d[i] = fmaf(y, ode_w2[j * NS + i], d[i]);
        }
        #pragma unroll
        for (int i = 0; i < NS; ++i) d[i] += ode_b2[i];
    };

    // ---------------- t = 0 outputs ----------------
    float amp[NK];
    {
        float eh = addc;
        #pragma unroll
        for (int k = 0; k < NK; ++k) {
            float xx = z[2 * k];
            amp[k] = xx * xx;
            eh = fmaf(xx, dw[k], eh);
        }
        out_eh[(size_t)b * NT] = eh;
        float* tp = out_tr + (size_t)b * NS;
        #pragma unroll
        for (int i = 0; i < NS; ++i) tp[i] = z[i];
    }

    // ---------------- integrate ----------------
    #pragma unroll 1
    for (int t = 1; t < NT; ++t) {
        const float dt  = t_eval[t] - t_eval[t - 1];
        const float hh  = dt * (1.0f / NSUB);
        const float hh2 = 0.5f * hh;
        const float hh6 = hh * (1.0f / 6.0f);
        #pragma unroll 1
        for (int ss = 0; ss < NSUB; ++ss) {
            float k1[NS], k2[NS], k3[NS], k4[NS], zt[NS];
            deriv(z, k1);
            #pragma unroll
            for (int i = 0; i < NS; ++i) zt[i] = fmaf(hh2, k1[i], z[i]);
            deriv(zt, k2);
            #pragma unroll
            for (int i = 0; i < NS; ++i) zt[i] = fmaf(hh2, k2[i], z[i]);
            deriv(zt, k3);
            #pragma unroll
            for (int i = 0; i < NS; ++i) zt[i] = fmaf(hh, k3[i], z[i]);
            deriv(zt, k4);
            #pragma unroll
            for (int i = 0; i < NS; ++i)
                z[i] += hh6 * (k1[i] + 2.0f * (k2[i] + k3[i]) + k4[i]);
        }
        float eh = addc;
        #pragma unroll
        for (int k = 0; k < NK; ++k) {
            float xx = z[2 * k];
            amp[k] = fmaf(xx, xx, amp[k]);
            eh = fmaf(xx, dw[k], eh);
        }
        out_eh[(size_t)b * NT + t] = eh;
        float* tp = out_tr + ((size_t)t * NB + b) * NS;
        #pragma unroll
        for (int i = 0; i < NS; ++i) tp[i] = z[i];
    }

    #pragma unroll
    for (int k = 0; k < NK; ++k)
        out_amp[(size_t)b * NK + k] = sqrtf(amp[k] * (1.0f / NT));
}

extern "C" void kernel_launch(void* const* d_in, const int* in_sizes, int n_in,
                              void* d_out, int out_size, void* d_ws, size_t ws_size,
                              hipStream_t stream) {
    pinod_kernel<<<NB / 64, 64, 0, stream>>>(
        (const float*)d_in[0],  (const float*)d_in[1],  (const float*)d_in[2],
        (const float*)d_in[3],  (const float*)d_in[4],  (const float*)d_in[5],
        (const float*)d_in[6],  (const float*)d_in[7],  (const float*)d_in[8],
        (const float*)d_in[9],  (const float*)d_in[10], (const float*)d_in[11],
        (const float*)d_in[12], (const float*)d_in[13], (const float*)d_in[14],
        (const float*)d_in[15], (const float*)d_in[16], (const float*)d_in[17],
        (const float*)d_in[18], (float*)d_out);
}

// Round 2
// 423.225 us; speedup vs baseline: 3.1070x; 3.1070x over previous
//
#include <hip/hip_runtime.h>
#include <math.h>

#define NB 32768
#define NT 48
#define NH 32
#define NOH 16
#define NK 3
#define NS 6
#define NSUB 4

// tanh(x) = 1 - 2/(exp(2x)+1): robust for all x
__device__ __forceinline__ float fast_tanh(float x) {
    float e = __builtin_amdgcn_exp2f(2.88539008177792681472f * x); // 2*log2(e)
    return 1.0f - 2.0f * __builtin_amdgcn_rcpf(e + 1.0f);
}

__device__ __forceinline__ float gelu_exact(float x) {
    return 0.5f * x * (1.0f + erff(x * 0.70710678118654752440f));
}

// sum across the 4-lane group (lanes grouped by consecutive lane id)
__device__ __forceinline__ float qsum(float v) {
    v += __shfl_xor(v, 1, 64);
    v += __shfl_xor(v, 2, 64);
    return v;
}

__global__ void __launch_bounds__(256, 2) pinod_kernel(
    const float* __restrict__ expr,
    const float* __restrict__ t_eval,
    const float* __restrict__ enc_w1,
    const float* __restrict__ enc_b1,
    const float* __restrict__ ln_g,
    const float* __restrict__ ln_b,
    const float* __restrict__ enc_w2,
    const float* __restrict__ enc_b2,
    const float* __restrict__ enc_w3,
    const float* __restrict__ enc_b3,
    const float* __restrict__ periods,
    const float* __restrict__ gammav,
    const float* __restrict__ ode_w1,
    const float* __restrict__ ode_b1,
    const float* __restrict__ ode_w2,
    const float* __restrict__ ode_b2,
    const float* __restrict__ dec_w,
    const float* __restrict__ dec_b,
    const float* __restrict__ baseline,
    float* __restrict__ out)
{
    const int tid  = blockIdx.x * 256 + threadIdx.x;
    const int lane = threadIdx.x & 63;
    const int sub  = lane & 3;        // which quarter of the hidden units
    const int b    = tid >> 2;        // element id
    const int base8 = sub * 8;        // encoder hidden slice [base8, base8+8)

    float* out_eh  = out;                                          // [NB][NT]
    float* out_tr  = out + (size_t)NB * NT;                        // [NT][NB][NS]
    float* out_amp = out + (size_t)NB * NT + (size_t)NT * NB * NS; // [NB][NK]

    // ================= encoder (split 4-way: 8 h-units per lane) =============
    float h1r[8];
    {
        const float4* bp = (const float4*)(enc_b1 + base8);
        float4 b0 = bp[0], b1v = bp[1];
        h1r[0] = b0.x; h1r[1] = b0.y; h1r[2] = b0.z; h1r[3] = b0.w;
        h1r[4] = b1v.x; h1r[5] = b1v.y; h1r[6] = b1v.z; h1r[7] = b1v.w;
    }
    const float4* xp = (const float4*)(expr + (size_t)b * NT);
    #pragma unroll 1
    for (int t4 = 0; t4 < NT / 4; ++t4) {
        float4 xq = xp[t4];
        float xs[4] = {xq.x, xq.y, xq.z, xq.w};
        #pragma unroll
        for (int u4 = 0; u4 < 4; ++u4) {
            int t = t4 * 4 + u4;
            const float4* wp = (const float4*)(enc_w1 + t * NH + base8);
            float4 wa = wp[0], wb = wp[1];
            float x = xs[u4];
            h1r[0] = fmaf(x, wa.x, h1r[0]); h1r[1] = fmaf(x, wa.y, h1r[1]);
            h1r[2] = fmaf(x, wa.z, h1r[2]); h1r[3] = fmaf(x, wa.w, h1r[3]);
            h1r[4] = fmaf(x, wb.x, h1r[4]); h1r[5] = fmaf(x, wb.y, h1r[5]);
            h1r[6] = fmaf(x, wb.z, h1r[6]); h1r[7] = fmaf(x, wb.w, h1r[7]);
        }
    }
    // layernorm over all 32 (cross-lane) + gelu
    {
        float s = 0.f;
        #pragma unroll
        for (int u = 0; u < 8; ++u) s += h1r[u];
        float mu = qsum(s) * (1.0f / NH);
        float v = 0.f;
        #pragma unroll
        for (int u = 0; u < 8; ++u) { float d = h1r[u] - mu; v = fmaf(d, d, v); }
        float var = qsum(v) * (1.0f / NH);
        float rstd = rsqrtf(var + 1e-5f);
        const float4* gp = (const float4*)(ln_g + base8);
        const float4* lp = (const float4*)(ln_b + base8);
        float4 g0 = gp[0], g1 = gp[1], l0 = lp[0], l1 = lp[1];
        float gg[8] = {g0.x,g0.y,g0.z,g0.w,g1.x,g1.y,g1.z,g1.w};
        float ll[8] = {l0.x,l0.y,l0.z,l0.w,l1.x,l1.y,l1.z,l1.w};
        #pragma unroll
        for (int u = 0; u < 8; ++u)
            h1r[u] = gelu_exact((h1r[u] - mu) * rstd * gg[u] + ll[u]);
    }
    // h2 = gelu(h1 @ w2 + b2): lane owns j2 in [base8, base8+8)
    float acc[8];
    {
        const float4* bp = (const float4*)(enc_b2 + base8);
        float4 b0 = bp[0], b1v = bp[1];
        acc[0] = b0.x; acc[1] = b0.y; acc[2] = b0.z; acc[3] = b0.w;
        acc[4] = b1v.x; acc[5] = b1v.y; acc[6] = b1v.z; acc[7] = b1v.w;
    }
    const int gbase = lane & ~3;
    #pragma unroll 1
    for (int g = 0; g < 4; ++g) {
        #pragma unroll
        for (int u = 0; u < 8; ++u) {
            float hv = __shfl(h1r[u], gbase + g, 64);
            int j = g * 8 + u;
            const float4* wp = (const float4*)(enc_w2 + j * NH + base8);
            float4 wa = wp[0], wb = wp[1];
            acc[0] = fmaf(hv, wa.x, acc[0]); acc[1] = fmaf(hv, wa.y, acc[1]);
            acc[2] = fmaf(hv, wa.z, acc[2]); acc[3] = fmaf(hv, wa.w, acc[3]);
            acc[4] = fmaf(hv, wb.x, acc[4]); acc[5] = fmaf(hv, wb.y, acc[5]);
            acc[6] = fmaf(hv, wb.z, acc[6]); acc[7] = fmaf(hv, wb.w, acc[7]);
        }
    }
    // z0 = gelu(acc) @ w3 + b3, reduced across lanes
    float z[NS];
    {
        float zp[NS] = {0.f, 0.f, 0.f, 0.f, 0.f, 0.f};
        #pragma unroll
        for (int m = 0; m < 8; ++m) {
            float gm = gelu_exact(acc[m]);
            const float2* wp = (const float2*)(enc_w3 + (base8 + m) * NS);
            float2 w0 = wp[0], w1 = wp[1], w2 = wp[2];
            zp[0] = fmaf(gm, w0.x, zp[0]); zp[1] = fmaf(gm, w0.y, zp[1]);
            zp[2] = fmaf(gm, w1.x, zp[2]); zp[3] = fmaf(gm, w1.y, zp[3]);
            zp[4] = fmaf(gm, w2.x, zp[4]); zp[5] = fmaf(gm, w2.y, zp[5]);
        }
        #pragma unroll
        for (int s2 = 0; s2 < NS; ++s2) z[s2] = qsum(zp[s2]) + enc_b3[s2];
    }

    // ============ ODE weights: lane owns 4 hidden units (VGPR-resident) ======
    const int base4 = sub * 4;
    float w1r[NS][4];
    #pragma unroll
    for (int i = 0; i < NS; ++i) {
        float4 w = *(const float4*)(ode_w1 + i * NOH + base4);
        w1r[i][0] = w.x; w1r[i][1] = w.y; w1r[i][2] = w.z; w1r[i][3] = w.w;
    }
    float b1r[4];
    {
        float4 w = *(const float4*)(ode_b1 + base4);
        b1r[0] = w.x; b1r[1] = w.y; b1r[2] = w.z; b1r[3] = w.w;
    }
    float w2r[4][NS];
    #pragma unroll
    for (int jj = 0; jj < 4; ++jj) {
        const float2* wp = (const float2*)(ode_w2 + (base4 + jj) * NS);
        float2 w0 = wp[0], w1 = wp[1], w2 = wp[2];
        w2r[jj][0] = w0.x; w2r[jj][1] = w0.y; w2r[jj][2] = w1.x;
        w2r[jj][3] = w1.y; w2r[jj][4] = w2.x; w2r[jj][5] = w2.y;
    }

    // uniform scalars (SGPR-resident)
    float om2[NK], tg[NK], dw[NK], b2u[NS];
    #pragma unroll
    for (int k = 0; k < NK; ++k) {
        float w = 6.28318530717958647693f / periods[k];
        om2[k] = w * w;
        tg[k]  = 2.0f * gammav[k];
        dw[k]  = dec_w[k];
    }
    #pragma unroll
    for (int i = 0; i < NS; ++i) b2u[i] = ode_b2[i];
    const float addc = dec_b[0] + baseline[0];

    auto deriv = [&](const float (&zz)[NS], float (&d)[NS]) {
        float pd[NS] = {0.f, 0.f, 0.f, 0.f, 0.f, 0.f};
        #pragma unroll
        for (int jj = 0; jj < 4; ++jj) {
            float a = b1r[jj];
            #pragma unroll
            for (int i = 0; i < NS; ++i) a = fmaf(zz[i], w1r[i][jj], a);
            float y = fast_tanh(a);
            #pragma unroll
            for (int i = 0; i < NS; ++i) pd[i] = fmaf(y, w2r[jj][i], pd[i]);
        }
        #pragma unroll
        for (int i = 0; i < NS; ++i) pd[i] = qsum(pd[i]);
        #pragma unroll
        for (int k = 0; k < NK; ++k) {
            float xx = zz[2 * k], vv = zz[2 * k + 1];
            d[2 * k]     = vv + pd[2 * k] + b2u[2 * k];
            d[2 * k + 1] = -om2[k] * xx - tg[k] * vv + pd[2 * k + 1] + b2u[2 * k + 1];
        }
    };

    // ================= t = 0 outputs =================
    float amp[NK];
    {
        float eh = addc;
        #pragma unroll
        for (int k = 0; k < NK; ++k) {
            float xx = z[2 * k];
            amp[k] = xx * xx;
            eh = fmaf(xx, dw[k], eh);
        }
        if (sub == 0) out_eh[(size_t)b * NT] = eh;
        if (sub < 3) {
            float a0 = (sub == 1) ? z[2] : z[0]; a0 = (sub == 2) ? z[4] : a0;
            float a1 = (sub == 1) ? z[3] : z[1]; a1 = (sub == 2) ? z[5] : a1;
            float2 st = {a0, a1};
            *(float2*)(out_tr + (size_t)b * NS + 2 * sub) = st;
        }
    }

    // ================= integrate =================
    #pragma unroll 1
    for (int t = 1; t < NT; ++t) {
        const float dt  = t_eval[t] - t_eval[t - 1];
        const float hh  = dt * (1.0f / NSUB);
        const float hh2 = 0.5f * hh;
        const float hh6 = hh * (1.0f / 6.0f);
        #pragma unroll 1
        for (int ss = 0; ss < NSUB; ++ss) {
            float d[NS], zt[NS], zsum[NS];
            deriv(z, d);                                        // k1
            #pragma unroll
            for (int i = 0; i < NS; ++i) { zsum[i] = d[i]; zt[i] = fmaf(hh2, d[i], z[i]); }
            deriv(zt, d);                                       // k2
            #pragma unroll
            for (int i = 0; i < NS; ++i) { zsum[i] = fmaf(2.f, d[i], zsum[i]); zt[i] = fmaf(hh2, d[i], z[i]); }
            deriv(zt, d);                                       // k3
            #pragma unroll
            for (int i = 0; i < NS; ++i) { zsum[i] = fmaf(2.f, d[i], zsum[i]); zt[i] = fmaf(hh, d[i], z[i]); }
            deriv(zt, d);                                       // k4
            #pragma unroll
            for (int i = 0; i < NS; ++i) z[i] = fmaf(hh6, zsum[i] + d[i], z[i]);
        }
        float eh = addc;
        #pragma unroll
        for (int k = 0; k < NK; ++k) {
            float xx = z[2 * k];
            amp[k] = fmaf(xx, xx, amp[k]);
            eh = fmaf(xx, dw[k], eh);
        }
        if (sub == 0) out_eh[(size_t)b * NT + t] = eh;
        if (sub < 3) {
            float a0 = (sub == 1) ? z[2] : z[0]; a0 = (sub == 2) ? z[4] : a0;
            float a1 = (sub == 1) ? z[3] : z[1]; a1 = (sub == 2) ? z[5] : a1;
            float2 st = {a0, a1};
            *(float2*)(out_tr + ((size_t)t * NB + b) * NS + 2 * sub) = st;
        }
    }

    if (sub < 3) {
        float av = (sub == 1) ? amp[1] : amp[0]; av = (sub == 2) ? amp[2] : av;
        out_amp[(size_t)b * NK + sub] = sqrtf(av * (1.0f / NT));
    }
}

extern "C" void kernel_launch(void* const* d_in, const int* in_sizes, int n_in,
                              void* d_out, int out_size, void* d_ws, size_t ws_size,
                              hipStream_t stream) {
    pinod_kernel<<<(NB * 4) / 256, 256, 0, stream>>>(
        (const float*)d_in[0],  (const float*)d_in[1],  (const float*)d_in[2],
        (const float*)d_in[3],  (const float*)d_in[4],  (const float*)d_in[5],
        (const float*)d_in[6],  (const float*)d_in[7],  (const float*)d_in[8],
        (const float*)d_in[9],  (const float*)d_in[10], (const float*)d_in[11],
        (const float*)d_in[12], (const float*)d_in[13], (const float*)d_in[14],
        (const float*)d_in[15], (const float*)d_in[16], (const float*)d_in[17],
        (const float*)d_in[18], (float*)d_out);
}